// Round 1
// baseline (1794.943 us; speedup 1.0000x reference)
//
#include <hip/hip_runtime.h>
#include <hip/hip_bf16.h>

#define NN 16384

using f32x4  = __attribute__((ext_vector_type(4))) float;
using bf16x8 = __attribute__((ext_vector_type(8))) __bf16;
using u16x8  = __attribute__((ext_vector_type(8))) unsigned short;

// Split f32 into bf16 hi (truncated) + bf16 lo (RNE of residual).
// |x - hi - lo| <= 2^-17 |x|  -> plenty for the 2% threshold.
__device__ __forceinline__ void split2(float x, unsigned short& h, unsigned short& l) {
  unsigned u  = __float_as_uint(x);
  unsigned hu = u & 0xFFFF0000u;
  float lf = x - __uint_as_float(hu);
  __bf16 lb = (__bf16)lf;
  h = (unsigned short)(hu >> 16);
  l = __builtin_bit_cast(unsigned short, lb);
}

// ---------------- K0: seq1|seq2 -> S^T hi/lo [128][16384] --------------------
__global__ void prep_seq(const float* __restrict__ seq1, const float* __restrict__ seq2,
                         unsigned short* __restrict__ Shi, unsigned short* __restrict__ Slo) {
  const int tid = threadIdx.x;
  const int r0  = blockIdx.x * 64;
  const float* seq = blockIdx.y ? seq2 : seq1;
  __shared__ float t[64][65];
  #pragma unroll
  for (int i = 0; i < 16; ++i) {
    int row = i * 4 + (tid >> 6);
    t[row][tid & 63] = seq[(long)(r0 + row) * 64 + (tid & 63)];
  }
  __syncthreads();
  #pragma unroll
  for (int i = 0; i < 16; ++i) {
    int col = i * 4 + (tid >> 6);
    int rr  = tid & 63;
    unsigned short h, l;
    split2(t[rr][col], h, l);
    long o = (long)(blockIdx.y * 64 + col) * NN + r0 + rr;
    Shi[o] = h; Slo[o] = l;
  }
}

// ---------------- big GEMM: P[z][ccols][NN] (C^T) = (adj @ X)^T --------------
// A: adj row-major f32.  B^T: [ccols][NN] bf16 hi/lo.  split-3 accumulate.
__launch_bounds__(256, 2)
__global__ void gemm_adj(const float* __restrict__ A,
                         const unsigned short* __restrict__ Bhi,
                         const unsigned short* __restrict__ Blo,
                         float* __restrict__ P, int ccols, int klen) {
  __shared__ unsigned short Ahs[128 * 40], Als[128 * 40], Xhs[128 * 40], Xls[128 * 40];
  const int tid  = threadIdx.x;
  const int lane = tid & 63;
  const int wave = tid >> 6;
  const int wr = wave & 1;     // adj-row half of tile
  const int wc = wave >> 1;    // x-col half of tile
  const int rtile = blockIdx.x * 128;
  const int ctile = blockIdx.y * 128;
  const int kbase = blockIdx.z * klen;

  const int srow  = tid >> 1;  // staging row (adj row / x col)
  const int shalf = tid & 1;   // 16-element k-half
  const int wbase = srow * 40 + shalf * 16;

  const float* aptr = A + (long)(rtile + srow) * NN + kbase + shalf * 16;
  const unsigned short* bhp = Bhi + (long)(ctile + srow) * NN + kbase + shalf * 16;
  const unsigned short* blp = Blo + (long)(ctile + srow) * NN + kbase + shalf * 16;

  f32x4 acc[4][4] = {};

  f32x4 a0 = *(const f32x4*)(aptr + 0);
  f32x4 a1 = *(const f32x4*)(aptr + 4);
  f32x4 a2 = *(const f32x4*)(aptr + 8);
  f32x4 a3 = *(const f32x4*)(aptr + 12);
  uint4 bh0 = *(const uint4*)(bhp);
  uint4 bh1 = *(const uint4*)(bhp + 8);
  uint4 bl0 = *(const uint4*)(blp);
  uint4 bl1 = *(const uint4*)(blp + 8);
  aptr += 32; bhp += 32; blp += 32;

  const int nsteps = klen / 32;
  for (int ks = 0; ks < nsteps; ++ks) {
    // convert adj f32 -> bf16 hi/lo (register-only; overlaps barrier wait)
    u16x8 h0, h1, l0, l1;
    #pragma unroll
    for (int i = 0; i < 16; ++i) {
      float x = i < 4 ? a0[i] : (i < 8 ? a1[i - 4] : (i < 12 ? a2[i - 8] : a3[i - 12]));
      unsigned short hh, ll;
      split2(x, hh, ll);
      if (i < 8) { h0[i] = hh; l0[i] = ll; }
      else       { h1[i - 8] = hh; l1[i - 8] = ll; }
    }
    __syncthreads();                       // prior frag reads complete
    *(u16x8*)&Ahs[wbase + 0] = h0;
    *(u16x8*)&Ahs[wbase + 8] = h1;
    *(u16x8*)&Als[wbase + 0] = l0;
    *(u16x8*)&Als[wbase + 8] = l1;
    *(uint4*)&Xhs[wbase + 0] = bh0;
    *(uint4*)&Xhs[wbase + 8] = bh1;
    *(uint4*)&Xls[wbase + 0] = bl0;
    *(uint4*)&Xls[wbase + 8] = bl1;
    __syncthreads();                       // LDS visible
    if (ks + 1 < nsteps) {                 // prefetch flies under MFMA phase
      a0 = *(const f32x4*)(aptr + 0);
      a1 = *(const f32x4*)(aptr + 4);
      a2 = *(const f32x4*)(aptr + 8);
      a3 = *(const f32x4*)(aptr + 12);
      bh0 = *(const uint4*)(bhp);
      bh1 = *(const uint4*)(bhp + 8);
      bl0 = *(const uint4*)(blp);
      bl1 = *(const uint4*)(blp + 8);
      aptr += 32; bhp += 32; blp += 32;
    }
    bf16x8 ahf[4], alf[4];
    #pragma unroll
    for (int ni = 0; ni < 4; ++ni) {
      int ar  = wr * 64 + ni * 16 + (lane & 15);
      int off = ar * 40 + (lane >> 4) * 8;
      ahf[ni] = *(const bf16x8*)&Ahs[off];
      alf[ni] = *(const bf16x8*)&Als[off];
    }
    #pragma unroll
    for (int mi = 0; mi < 4; ++mi) {
      int xc  = wc * 64 + mi * 16 + (lane & 15);
      int off = xc * 40 + (lane >> 4) * 8;
      bf16x8 xh = *(const bf16x8*)&Xhs[off];
      bf16x8 xl = *(const bf16x8*)&Xls[off];
      #pragma unroll
      for (int ni = 0; ni < 4; ++ni) {
        acc[mi][ni] = __builtin_amdgcn_mfma_f32_16x16x32_bf16(xh, ahf[ni], acc[mi][ni], 0, 0, 0);
        acc[mi][ni] = __builtin_amdgcn_mfma_f32_16x16x32_bf16(xl, ahf[ni], acc[mi][ni], 0, 0, 0);
        acc[mi][ni] = __builtin_amdgcn_mfma_f32_16x16x32_bf16(xh, alf[ni], acc[mi][ni], 0, 0, 0);
      }
    }
  }
  // epilogue: C/D frag  col=lane&15 (adj row), row=(lane>>4)*4+j (x col)
  float* out = P + (long)blockIdx.z * ccols * NN;
  #pragma unroll
  for (int mi = 0; mi < 4; ++mi) {
    int xc = ctile + wc * 64 + mi * 16 + ((lane >> 4) << 2);
    #pragma unroll
    for (int ni = 0; ni < 4; ++ni) {
      int ar = rtile + wr * 64 + ni * 16 + (lane & 15);
      #pragma unroll
      for (int j = 0; j < 4; ++j)
        out[(long)(xc + j) * NN + ar] = acc[mi][ni][j];
    }
  }
}

// ---------------- K2a: H1^T = relu(T1 @ w1 + b1), T1 = P0+P1 -----------------
__global__ void post1a(const float* __restrict__ P, const float* __restrict__ w1,
                       const float* __restrict__ b1, float* __restrict__ H1T) {
  const int r  = blockIdx.x * 256 + threadIdx.x;
  const int e  = blockIdx.y;
  const int j0 = blockIdx.z * 66;
  float acc[66];
  #pragma unroll
  for (int jj = 0; jj < 66; ++jj) acc[jj] = b1[j0 + jj];
  for (int k = 0; k < 64; ++k) {
    float tv = P[(long)(e * 64 + k) * NN + r] + P[(long)(128 + e * 64 + k) * NN + r];
    #pragma unroll
    for (int jj = 0; jj < 66; ++jj)
      acc[jj] = fmaf(tv, w1[k * 264 + j0 + jj], acc[jj]);
  }
  #pragma unroll
  for (int jj = 0; jj < 66; ++jj)
    H1T[(long)(e * 264 + j0 + jj) * NN + r] = fmaxf(acc[jj], 0.f);
}

// ---------------- K2b: G^T hi/lo [384][NN] = (H1 @ w2)^T, rows 164..191 pad 0
__global__ void post1b(const float* __restrict__ H1T, const float* __restrict__ w2,
                       unsigned short* __restrict__ Ghi, unsigned short* __restrict__ Glo) {
  const int r  = blockIdx.x * 256 + threadIdx.x;
  const int e  = blockIdx.y;
  const int q0 = blockIdx.z * 41;
  float acc[41] = {};
  for (int j = 0; j < 264; ++j) {
    float h = H1T[(long)(e * 264 + j) * NN + r];
    #pragma unroll
    for (int qq = 0; qq < 41; ++qq)
      acc[qq] = fmaf(h, w2[j * 164 + q0 + qq], acc[qq]);
  }
  #pragma unroll
  for (int qq = 0; qq < 41; ++qq) {
    unsigned short h, l;
    split2(acc[qq], h, l);
    long o = (long)(e * 192 + q0 + qq) * NN + r;
    Ghi[o] = h; Glo[o] = l;
  }
  if (blockIdx.z == 3) {
    for (int q = 164; q < 192; ++q) {
      long o = (long)(e * 192 + q) * NN + r;
      Ghi[o] = 0; Glo[o] = 0;
    }
  }
}

// ---------------- K5: F^T hi/lo = (relu(T2+b2) @ w3)^T -----------------------
__global__ void post2(const float* __restrict__ P, const float* __restrict__ w3,
                      const float* __restrict__ b2,
                      unsigned short* __restrict__ Fhi, unsigned short* __restrict__ Flo) {
  const int r = blockIdx.x * 256 + threadIdx.x;
  const int e = blockIdx.y;
  float f[64] = {};
  for (int j = 0; j < 164; ++j) {
    float h = P[(long)(e * 192 + j) * NN + r] + P[(long)(384 + e * 192 + j) * NN + r] + b2[j];
    h = fmaxf(h, 0.f);
    #pragma unroll
    for (int q = 0; q < 64; ++q) f[q] = fmaf(h, w3[j * 64 + q], f[q]);
  }
  #pragma unroll
  for (int q = 0; q < 64; ++q) {
    unsigned short h, l;
    split2(f[q], h, l);
    long o = (long)(e * 64 + q) * NN + r;
    Fhi[o] = h; Flo[o] = l;
  }
}

// ---------------- K7: H3^T = relu(T3 + b3) -----------------------------------
__global__ void post3(const float* __restrict__ P, const float* __restrict__ b3,
                      float* __restrict__ H3T) {
  const int r = blockIdx.x * 256 + threadIdx.x;
  const int e = blockIdx.y;
  #pragma unroll
  for (int q = 0; q < 64; ++q) {
    float v = P[(long)(e * 64 + q) * NN + r] + P[(long)(128 + e * 64 + q) * NN + r] + b3[q];
    H3T[(long)(e * 64 + q) * NN + r] = fmaxf(v, 0.f);
  }
}

// ---------------- K8: column sums of encoder-1 H3 ----------------------------
__global__ void colsum(const float* __restrict__ H3T, float* __restrict__ sums) {
  const int c = blockIdx.x;       // 0..63
  const float* row = H3T + (long)c * NN;
  float s = 0.f;
  for (int i = threadIdx.x; i < NN; i += 256) s += row[i];
  __shared__ float red[256];
  red[threadIdx.x] = s;
  __syncthreads();
  for (int off = 128; off > 0; off >>= 1) {
    if (threadIdx.x < off) red[threadIdx.x] += red[threadIdx.x + off];
    __syncthreads();
  }
  if (threadIdx.x == 0) sums[c] = red[0];
}

// ---------------- K9: c = sigmoid(mean), cw = wd @ c -------------------------
__global__ void make_cw(const float* __restrict__ sums, const float* __restrict__ wd,
                        float* __restrict__ cw) {
  __shared__ float cv[64];
  const int t = threadIdx.x;      // 64 threads
  cv[t] = 1.f / (1.f + expf(-sums[t] / 16384.f));
  __syncthreads();
  float a = 0.f;
  for (int d = 0; d < 64; ++d) a += cv[d] * wd[t * 64 + d];
  cw[t] = a;
}

// ---------------- K10: scores -------------------------------------------------
__global__ void score(const float* __restrict__ H3T, const float* __restrict__ cw,
                      const float* __restrict__ bdp, const float* __restrict__ sb1,
                      const float* __restrict__ sb2, float* __restrict__ out) {
  const int idx = blockIdx.x * 256 + threadIdx.x;   // 0..32767
  const int e = idx >> 14, r = idx & (NN - 1);
  float acc = bdp[0] + (e ? sb2[r] : sb1[r]);
  const float* base = H3T + (long)e * 64 * NN + r;
  #pragma unroll
  for (int j = 0; j < 64; ++j) acc = fmaf(base[(long)j * NN], cw[j], acc);
  out[idx] = acc;
}

extern "C" void kernel_launch(void* const* d_in, const int* in_sizes, int n_in,
                              void* d_out, int out_size, void* d_ws, size_t ws_size,
                              hipStream_t stream) {
  const float* seq1 = (const float*)d_in[0];
  const float* seq2 = (const float*)d_in[1];
  const float* adj  = (const float*)d_in[2];
  const float* sb1  = (const float*)d_in[3];
  const float* sb2  = (const float*)d_in[4];
  const float* w1   = (const float*)d_in[5];
  const float* b1   = (const float*)d_in[6];
  const float* w2   = (const float*)d_in[7];
  const float* b2   = (const float*)d_in[8];
  const float* w3   = (const float*)d_in[9];
  const float* b3   = (const float*)d_in[10];
  const float* wd   = (const float*)d_in[11];
  const float* bd   = (const float*)d_in[12];
  float* out = (float*)d_out;

  // workspace layout (~121 MB total)
  char* ws = (char*)d_ws;
  unsigned short* Shi = (unsigned short*)(ws + 0);          //  4,194,304
  unsigned short* Slo = (unsigned short*)(ws + 4194304);    //  4,194,304
  float*          Pp  = (float*)(ws + 8388608);             // 50,331,648
  unsigned short* Ghi = (unsigned short*)(ws + 58720256);   // 12,582,912
  unsigned short* Glo = (unsigned short*)(ws + 71303168);   // 12,582,912
  float*          H1T = (float*)(ws + 83886080);            // 34,603,008
  float*          H3T = (float*)(ws + 118489088);           //  8,388,608
  float*          sums= (float*)(ws + 126877696);           //        256
  float*          cw  = (float*)(ws + 126877952);           //        256
  unsigned short* Fhi = Shi;  // S dead after layer-1 GEMM
  unsigned short* Flo = Slo;

  prep_seq<<<dim3(256, 2), 256, 0, stream>>>(seq1, seq2, Shi, Slo);
  gemm_adj<<<dim3(128, 1, 2), 256, 0, stream>>>(adj, Shi, Slo, Pp, 128, 8192);
  post1a  <<<dim3(64, 2, 4), 256, 0, stream>>>(Pp, w1, b1, H1T);
  post1b  <<<dim3(64, 2, 4), 256, 0, stream>>>(H1T, w2, Ghi, Glo);
  gemm_adj<<<dim3(128, 3, 2), 256, 0, stream>>>(adj, Ghi, Glo, Pp, 384, 8192);
  post2   <<<dim3(64, 2), 256, 0, stream>>>(Pp, w3, b2, Fhi, Flo);
  gemm_adj<<<dim3(128, 1, 2), 256, 0, stream>>>(adj, Fhi, Flo, Pp, 128, 8192);
  post3   <<<dim3(64, 2), 256, 0, stream>>>(Pp, b3, H3T);
  colsum  <<<64, 256, 0, stream>>>(H3T, sums);
  make_cw <<<1, 64, 0, stream>>>(sums, wd, cw);
  score   <<<128, 256, 0, stream>>>(H3T, cw, bd, sb1, sb2, out);
}

// Round 2
// 1613.470 us; speedup vs baseline: 1.1125x; 1.1125x over previous
//
#include <hip/hip_runtime.h>
#include <hip/hip_bf16.h>

#define NN 16384

using f32x4  = __attribute__((ext_vector_type(4))) float;
using bf16x8 = __attribute__((ext_vector_type(8))) __bf16;
using u16x8  = __attribute__((ext_vector_type(8))) unsigned short;

// Split f32 into bf16 hi (truncated) + bf16 lo (RNE of residual).
// |x - hi - lo| <= 2^-17 |x|  -> plenty for the 2% threshold.
__device__ __forceinline__ void split2(float x, unsigned short& h, unsigned short& l) {
  unsigned u  = __float_as_uint(x);
  unsigned hu = u & 0xFFFF0000u;
  float lf = x - __uint_as_float(hu);
  __bf16 lb = (__bf16)lf;
  h = (unsigned short)(hu >> 16);
  l = __builtin_bit_cast(unsigned short, lb);
}

// ---------------- K0: seq1|seq2 -> S^T hi/lo [128][16384] --------------------
__global__ void prep_seq(const float* __restrict__ seq1, const float* __restrict__ seq2,
                         unsigned short* __restrict__ Shi, unsigned short* __restrict__ Slo) {
  const int tid = threadIdx.x;
  const int r0  = blockIdx.x * 64;
  const float* seq = blockIdx.y ? seq2 : seq1;
  __shared__ float t[64][65];
  #pragma unroll
  for (int i = 0; i < 16; ++i) {
    int row = i * 4 + (tid >> 6);
    t[row][tid & 63] = seq[(long)(r0 + row) * 64 + (tid & 63)];
  }
  __syncthreads();
  #pragma unroll
  for (int i = 0; i < 16; ++i) {
    int col = i * 4 + (tid >> 6);
    int rr  = tid & 63;
    unsigned short h, l;
    split2(t[rr][col], h, l);
    long o = (long)(blockIdx.y * 64 + col) * NN + r0 + rr;
    Shi[o] = h; Slo[o] = l;
  }
}

// ---------------- big GEMM: P[z][ccols][NN] (C^T) = (adj @ X)^T --------------
// A: adj row-major f32.  B^T: [ccols][NN] bf16 hi/lo.  split-3 accumulate.
__launch_bounds__(256, 2)
__global__ void gemm_adj(const float* __restrict__ A,
                         const unsigned short* __restrict__ Bhi,
                         const unsigned short* __restrict__ Blo,
                         float* __restrict__ P, int ccols, int klen) {
  __shared__ unsigned short Ahs[128 * 40], Als[128 * 40], Xhs[128 * 40], Xls[128 * 40];
  const int tid  = threadIdx.x;
  const int lane = tid & 63;
  const int wave = tid >> 6;
  const int wr = wave & 1;     // adj-row half of tile
  const int wc = wave >> 1;    // x-col half of tile
  const int rtile = blockIdx.x * 128;
  const int ctile = blockIdx.y * 128;
  const int kbase = blockIdx.z * klen;

  const int srow  = tid >> 1;  // staging row (adj row / x col)
  const int shalf = tid & 1;   // 16-element k-half
  const int wbase = srow * 40 + shalf * 16;

  const float* aptr = A + (long)(rtile + srow) * NN + kbase + shalf * 16;
  const unsigned short* bhp = Bhi + (long)(ctile + srow) * NN + kbase + shalf * 16;
  const unsigned short* blp = Blo + (long)(ctile + srow) * NN + kbase + shalf * 16;

  f32x4 acc[4][4] = {};

  f32x4 a0 = *(const f32x4*)(aptr + 0);
  f32x4 a1 = *(const f32x4*)(aptr + 4);
  f32x4 a2 = *(const f32x4*)(aptr + 8);
  f32x4 a3 = *(const f32x4*)(aptr + 12);
  uint4 bh0 = *(const uint4*)(bhp);
  uint4 bh1 = *(const uint4*)(bhp + 8);
  uint4 bl0 = *(const uint4*)(blp);
  uint4 bl1 = *(const uint4*)(blp + 8);
  aptr += 32; bhp += 32; blp += 32;

  const int nsteps = klen / 32;
  for (int ks = 0; ks < nsteps; ++ks) {
    // convert adj f32 -> bf16 hi/lo (register-only; overlaps barrier wait)
    u16x8 h0, h1, l0, l1;
    #pragma unroll
    for (int i = 0; i < 16; ++i) {
      float x = i < 4 ? a0[i] : (i < 8 ? a1[i - 4] : (i < 12 ? a2[i - 8] : a3[i - 12]));
      unsigned short hh, ll;
      split2(x, hh, ll);
      if (i < 8) { h0[i] = hh; l0[i] = ll; }
      else       { h1[i - 8] = hh; l1[i - 8] = ll; }
    }
    __syncthreads();                       // prior frag reads complete
    *(u16x8*)&Ahs[wbase + 0] = h0;
    *(u16x8*)&Ahs[wbase + 8] = h1;
    *(u16x8*)&Als[wbase + 0] = l0;
    *(u16x8*)&Als[wbase + 8] = l1;
    *(uint4*)&Xhs[wbase + 0] = bh0;
    *(uint4*)&Xhs[wbase + 8] = bh1;
    *(uint4*)&Xls[wbase + 0] = bl0;
    *(uint4*)&Xls[wbase + 8] = bl1;
    if (ks + 1 < nsteps) {                 // issue before barrier: loads fly under
      a0 = *(const f32x4*)(aptr + 0);      // barrier-wait + MFMA phase
      a1 = *(const f32x4*)(aptr + 4);
      a2 = *(const f32x4*)(aptr + 8);
      a3 = *(const f32x4*)(aptr + 12);
      bh0 = *(const uint4*)(bhp);
      bh1 = *(const uint4*)(bhp + 8);
      bl0 = *(const uint4*)(blp);
      bl1 = *(const uint4*)(blp + 8);
      aptr += 32; bhp += 32; blp += 32;
    }
    __syncthreads();                       // LDS visible
    bf16x8 ahf[4], alf[4];
    #pragma unroll
    for (int ni = 0; ni < 4; ++ni) {
      int ar  = wr * 64 + ni * 16 + (lane & 15);
      int off = ar * 40 + (lane >> 4) * 8;
      ahf[ni] = *(const bf16x8*)&Ahs[off];
      alf[ni] = *(const bf16x8*)&Als[off];
    }
    #pragma unroll
    for (int mi = 0; mi < 4; ++mi) {
      int xc  = wc * 64 + mi * 16 + (lane & 15);
      int off = xc * 40 + (lane >> 4) * 8;
      bf16x8 xh = *(const bf16x8*)&Xhs[off];
      bf16x8 xl = *(const bf16x8*)&Xls[off];
      #pragma unroll
      for (int ni = 0; ni < 4; ++ni) {
        acc[mi][ni] = __builtin_amdgcn_mfma_f32_16x16x32_bf16(xh, ahf[ni], acc[mi][ni], 0, 0, 0);
        acc[mi][ni] = __builtin_amdgcn_mfma_f32_16x16x32_bf16(xl, ahf[ni], acc[mi][ni], 0, 0, 0);
        acc[mi][ni] = __builtin_amdgcn_mfma_f32_16x16x32_bf16(xh, alf[ni], acc[mi][ni], 0, 0, 0);
      }
    }
  }
  // epilogue: C/D frag  col=lane&15 (adj row), row=(lane>>4)*4+j (x col)
  float* out = P + (long)blockIdx.z * ccols * NN;
  #pragma unroll
  for (int mi = 0; mi < 4; ++mi) {
    int xc = ctile + wc * 64 + mi * 16 + ((lane >> 4) << 2);
    #pragma unroll
    for (int ni = 0; ni < 4; ++ni) {
      int ar = rtile + wr * 64 + ni * 16 + (lane & 15);
      #pragma unroll
      for (int j = 0; j < 4; ++j)
        out[(long)(xc + j) * NN + ar] = acc[mi][ni][j];
    }
  }
}

// ---------------- K2a: H1^T = relu(T1 @ w1 + b1), T1 = sum_z P[z] ------------
__global__ void post1a(const float* __restrict__ P, const float* __restrict__ w1,
                       const float* __restrict__ b1, float* __restrict__ H1T) {
  const int r  = blockIdx.x * 256 + threadIdx.x;
  const int e  = blockIdx.y;
  const int j0 = blockIdx.z * 66;
  float acc[66];
  #pragma unroll
  for (int jj = 0; jj < 66; ++jj) acc[jj] = b1[j0 + jj];
  for (int k = 0; k < 64; ++k) {
    float tv = 0.f;
    #pragma unroll
    for (int z = 0; z < 8; ++z)
      tv += P[(long)(z * 128 + e * 64 + k) * NN + r];
    #pragma unroll
    for (int jj = 0; jj < 66; ++jj)
      acc[jj] = fmaf(tv, w1[k * 264 + j0 + jj], acc[jj]);
  }
  #pragma unroll
  for (int jj = 0; jj < 66; ++jj)
    H1T[(long)(e * 264 + j0 + jj) * NN + r] = fmaxf(acc[jj], 0.f);
}

// ---------------- K2b: G^T hi/lo [384][NN] = (H1 @ w2)^T, rows 164..191 pad 0
__global__ void post1b(const float* __restrict__ H1T, const float* __restrict__ w2,
                       unsigned short* __restrict__ Ghi, unsigned short* __restrict__ Glo) {
  const int r  = blockIdx.x * 256 + threadIdx.x;
  const int e  = blockIdx.y;
  const int q0 = blockIdx.z * 41;
  float acc[41] = {};
  for (int j = 0; j < 264; ++j) {
    float h = H1T[(long)(e * 264 + j) * NN + r];
    #pragma unroll
    for (int qq = 0; qq < 41; ++qq)
      acc[qq] = fmaf(h, w2[j * 164 + q0 + qq], acc[qq]);
  }
  #pragma unroll
  for (int qq = 0; qq < 41; ++qq) {
    unsigned short h, l;
    split2(acc[qq], h, l);
    long o = (long)(e * 192 + q0 + qq) * NN + r;
    Ghi[o] = h; Glo[o] = l;
  }
  if (blockIdx.z == 3) {
    for (int q = 164; q < 192; ++q) {
      long o = (long)(e * 192 + q) * NN + r;
      Ghi[o] = 0; Glo[o] = 0;
    }
  }
}

// ---------------- K5: F^T hi/lo = (relu(T2+b2) @ w3)^T -----------------------
__global__ void post2(const float* __restrict__ P, const float* __restrict__ w3,
                      const float* __restrict__ b2,
                      unsigned short* __restrict__ Fhi, unsigned short* __restrict__ Flo) {
  const int r = blockIdx.x * 256 + threadIdx.x;
  const int e = blockIdx.y;
  float f[64] = {};
  for (int j = 0; j < 164; ++j) {
    float h = P[(long)(e * 192 + j) * NN + r] + P[(long)(384 + e * 192 + j) * NN + r] + b2[j];
    h = fmaxf(h, 0.f);
    #pragma unroll
    for (int q = 0; q < 64; ++q) f[q] = fmaf(h, w3[j * 64 + q], f[q]);
  }
  #pragma unroll
  for (int q = 0; q < 64; ++q) {
    unsigned short h, l;
    split2(f[q], h, l);
    long o = (long)(e * 64 + q) * NN + r;
    Fhi[o] = h; Flo[o] = l;
  }
}

// ---------------- K7: H3^T = relu(sum_z T3 + b3) -----------------------------
__global__ void post3(const float* __restrict__ P, const float* __restrict__ b3,
                      float* __restrict__ H3T) {
  const int r = blockIdx.x * 256 + threadIdx.x;
  const int e = blockIdx.y;
  #pragma unroll
  for (int q = 0; q < 64; ++q) {
    float v = b3[q];
    #pragma unroll
    for (int z = 0; z < 8; ++z)
      v += P[(long)(z * 128 + e * 64 + q) * NN + r];
    H3T[(long)(e * 64 + q) * NN + r] = fmaxf(v, 0.f);
  }
}

// ---------------- K8: column sums of encoder-1 H3 ----------------------------
__global__ void colsum(const float* __restrict__ H3T, float* __restrict__ sums) {
  const int c = blockIdx.x;       // 0..63
  const float* row = H3T + (long)c * NN;
  float s = 0.f;
  for (int i = threadIdx.x; i < NN; i += 256) s += row[i];
  __shared__ float red[256];
  red[threadIdx.x] = s;
  __syncthreads();
  for (int off = 128; off > 0; off >>= 1) {
    if (threadIdx.x < off) red[threadIdx.x] += red[threadIdx.x + off];
    __syncthreads();
  }
  if (threadIdx.x == 0) sums[c] = red[0];
}

// ---------------- K9: c = sigmoid(mean), cw = wd @ c -------------------------
__global__ void make_cw(const float* __restrict__ sums, const float* __restrict__ wd,
                        float* __restrict__ cw) {
  __shared__ float cv[64];
  const int t = threadIdx.x;      // 64 threads
  cv[t] = 1.f / (1.f + expf(-sums[t] / 16384.f));
  __syncthreads();
  float a = 0.f;
  for (int d = 0; d < 64; ++d) a += cv[d] * wd[t * 64 + d];
  cw[t] = a;
}

// ---------------- K10: scores -------------------------------------------------
__global__ void score(const float* __restrict__ H3T, const float* __restrict__ cw,
                      const float* __restrict__ bdp, const float* __restrict__ sb1,
                      const float* __restrict__ sb2, float* __restrict__ out) {
  const int idx = blockIdx.x * 256 + threadIdx.x;   // 0..32767
  const int e = idx >> 14, r = idx & (NN - 1);
  float acc = bdp[0] + (e ? sb2[r] : sb1[r]);
  const float* base = H3T + (long)e * 64 * NN + r;
  #pragma unroll
  for (int j = 0; j < 64; ++j) acc = fmaf(base[(long)j * NN], cw[j], acc);
  out[idx] = acc;
}

extern "C" void kernel_launch(void* const* d_in, const int* in_sizes, int n_in,
                              void* d_out, int out_size, void* d_ws, size_t ws_size,
                              hipStream_t stream) {
  const float* seq1 = (const float*)d_in[0];
  const float* seq2 = (const float*)d_in[1];
  const float* adj  = (const float*)d_in[2];
  const float* sb1  = (const float*)d_in[3];
  const float* sb2  = (const float*)d_in[4];
  const float* w1   = (const float*)d_in[5];
  const float* b1   = (const float*)d_in[6];
  const float* w2   = (const float*)d_in[7];
  const float* b2   = (const float*)d_in[8];
  const float* w3   = (const float*)d_in[9];
  const float* b3   = (const float*)d_in[10];
  const float* wd   = (const float*)d_in[11];
  const float* bd   = (const float*)d_in[12];
  float* out = (float*)d_out;

  // workspace layout (~127 MB total)
  // P for layers 1/3 (z=8): 67,108,864 B at 8,388,608 -> 75,497,472; overlaps
  // Ghi/Glo/H1T region ONLY while those are dead. Layer-2 P (z=2): 50,331,648 B
  // ends at 58,720,256 == Ghi start (its input) -- no overlap.
  char* ws = (char*)d_ws;
  unsigned short* Shi = (unsigned short*)(ws + 0);          //  4,194,304
  unsigned short* Slo = (unsigned short*)(ws + 4194304);    //  4,194,304
  float*          Pp  = (float*)(ws + 8388608);             // up to 67,108,864
  unsigned short* Ghi = (unsigned short*)(ws + 58720256);   // 12,582,912
  unsigned short* Glo = (unsigned short*)(ws + 71303168);   // 12,582,912
  float*          H1T = (float*)(ws + 83886080);            // 34,603,008
  float*          H3T = (float*)(ws + 118489088);           //  8,388,608
  float*          sums= (float*)(ws + 126877696);           //        256
  float*          cw  = (float*)(ws + 126877952);           //        256
  unsigned short* Fhi = Shi;  // S dead after layer-1 GEMM
  unsigned short* Flo = Slo;

  prep_seq<<<dim3(256, 2), 256, 0, stream>>>(seq1, seq2, Shi, Slo);
  gemm_adj<<<dim3(128, 1, 8), 256, 0, stream>>>(adj, Shi, Slo, Pp, 128, 2048);
  post1a  <<<dim3(64, 2, 4), 256, 0, stream>>>(Pp, w1, b1, H1T);
  post1b  <<<dim3(64, 2, 4), 256, 0, stream>>>(H1T, w2, Ghi, Glo);
  gemm_adj<<<dim3(128, 3, 2), 256, 0, stream>>>(adj, Ghi, Glo, Pp, 384, 8192);
  post2   <<<dim3(64, 2), 256, 0, stream>>>(Pp, w3, b2, Fhi, Flo);
  gemm_adj<<<dim3(128, 1, 8), 256, 0, stream>>>(adj, Fhi, Flo, Pp, 128, 2048);
  post3   <<<dim3(64, 2), 256, 0, stream>>>(Pp, b3, H3T);
  colsum  <<<64, 256, 0, stream>>>(H3T, sums);
  make_cw <<<1, 64, 0, stream>>>(sums, wd, cw);
  score   <<<128, 256, 0, stream>>>(H3T, cw, bd, sb1, sb2, out);
}

// Round 3
// 1249.540 us; speedup vs baseline: 1.4365x; 1.2913x over previous
//
#include <hip/hip_runtime.h>
#include <hip/hip_bf16.h>

#define NN 16384

using f32x4  = __attribute__((ext_vector_type(4))) float;
using bf16x8 = __attribute__((ext_vector_type(8))) __bf16;
using u16x8  = __attribute__((ext_vector_type(8))) unsigned short;

// Split f32 into bf16 hi (truncated) + bf16 lo (RNE of residual).
__device__ __forceinline__ void split2(float x, unsigned short& h, unsigned short& l) {
  unsigned u  = __float_as_uint(x);
  unsigned hu = u & 0xFFFF0000u;
  float lf = x - __uint_as_float(hu);
  __bf16 lb = (__bf16)lf;
  h = (unsigned short)(hu >> 16);
  l = __builtin_bit_cast(unsigned short, lb);
}

__device__ __forceinline__ void gload_lds16(const void* g, void* l) {
  __builtin_amdgcn_global_load_lds(
      (const __attribute__((address_space(1))) unsigned*)g,
      (__attribute__((address_space(3))) unsigned*)l, 16, 0, 0);
}

// ---------------- K0: seq1|seq2 -> S^T hi/lo [128][16384] --------------------
__global__ void prep_seq(const float* __restrict__ seq1, const float* __restrict__ seq2,
                         unsigned short* __restrict__ Shi, unsigned short* __restrict__ Slo) {
  const int tid = threadIdx.x;
  const int r0  = blockIdx.x * 64;
  const float* seq = blockIdx.y ? seq2 : seq1;
  __shared__ float t[64][65];
  #pragma unroll
  for (int i = 0; i < 16; ++i) {
    int row = i * 4 + (tid >> 6);
    t[row][tid & 63] = seq[(long)(r0 + row) * 64 + (tid & 63)];
  }
  __syncthreads();
  #pragma unroll
  for (int i = 0; i < 16; ++i) {
    int col = i * 4 + (tid >> 6);
    int rr  = tid & 63;
    unsigned short h, l;
    split2(t[rr][col], h, l);
    long o = (long)(blockIdx.y * 64 + col) * NN + r0 + rr;
    Shi[o] = h; Slo[o] = l;
  }
}

// ---------------- layer-1 GEMM (split-3 hi/lo, proven): P = (adj @ X)^T ------
__launch_bounds__(256, 2)
__global__ void gemm_adj(const float* __restrict__ A,
                         const unsigned short* __restrict__ Bhi,
                         const unsigned short* __restrict__ Blo,
                         float* __restrict__ P, int ccols, int klen) {
  __shared__ unsigned short Ahs[128 * 40], Als[128 * 40], Xhs[128 * 40], Xls[128 * 40];
  const int tid  = threadIdx.x;
  const int lane = tid & 63;
  const int wave = tid >> 6;
  const int wr = wave & 1;
  const int wc = wave >> 1;
  const int rtile = blockIdx.x * 128;
  const int ctile = blockIdx.y * 128;
  const int kbase = blockIdx.z * klen;

  const int srow  = tid >> 1;
  const int shalf = tid & 1;
  const int wbase = srow * 40 + shalf * 16;

  const float* aptr = A + (long)(rtile + srow) * NN + kbase + shalf * 16;
  const unsigned short* bhp = Bhi + (long)(ctile + srow) * NN + kbase + shalf * 16;
  const unsigned short* blp = Blo + (long)(ctile + srow) * NN + kbase + shalf * 16;

  f32x4 acc[4][4] = {};

  f32x4 a0 = *(const f32x4*)(aptr + 0);
  f32x4 a1 = *(const f32x4*)(aptr + 4);
  f32x4 a2 = *(const f32x4*)(aptr + 8);
  f32x4 a3 = *(const f32x4*)(aptr + 12);
  uint4 bh0 = *(const uint4*)(bhp);
  uint4 bh1 = *(const uint4*)(bhp + 8);
  uint4 bl0 = *(const uint4*)(blp);
  uint4 bl1 = *(const uint4*)(blp + 8);
  aptr += 32; bhp += 32; blp += 32;

  const int nsteps = klen / 32;
  for (int ks = 0; ks < nsteps; ++ks) {
    u16x8 h0, h1, l0, l1;
    #pragma unroll
    for (int i = 0; i < 16; ++i) {
      float x = i < 4 ? a0[i] : (i < 8 ? a1[i - 4] : (i < 12 ? a2[i - 8] : a3[i - 12]));
      unsigned short hh, ll;
      split2(x, hh, ll);
      if (i < 8) { h0[i] = hh; l0[i] = ll; }
      else       { h1[i - 8] = hh; l1[i - 8] = ll; }
    }
    __syncthreads();
    *(u16x8*)&Ahs[wbase + 0] = h0;
    *(u16x8*)&Ahs[wbase + 8] = h1;
    *(u16x8*)&Als[wbase + 0] = l0;
    *(u16x8*)&Als[wbase + 8] = l1;
    *(uint4*)&Xhs[wbase + 0] = bh0;
    *(uint4*)&Xhs[wbase + 8] = bh1;
    *(uint4*)&Xls[wbase + 0] = bl0;
    *(uint4*)&Xls[wbase + 8] = bl1;
    if (ks + 1 < nsteps) {
      a0 = *(const f32x4*)(aptr + 0);
      a1 = *(const f32x4*)(aptr + 4);
      a2 = *(const f32x4*)(aptr + 8);
      a3 = *(const f32x4*)(aptr + 12);
      bh0 = *(const uint4*)(bhp);
      bh1 = *(const uint4*)(bhp + 8);
      bl0 = *(const uint4*)(blp);
      bl1 = *(const uint4*)(blp + 8);
      aptr += 32; bhp += 32; blp += 32;
    }
    __syncthreads();
    bf16x8 ahf[4], alf[4];
    #pragma unroll
    for (int ni = 0; ni < 4; ++ni) {
      int ar  = wr * 64 + ni * 16 + (lane & 15);
      int off = ar * 40 + (lane >> 4) * 8;
      ahf[ni] = *(const bf16x8*)&Ahs[off];
      alf[ni] = *(const bf16x8*)&Als[off];
    }
    #pragma unroll
    for (int mi = 0; mi < 4; ++mi) {
      int xc  = wc * 64 + mi * 16 + (lane & 15);
      int off = xc * 40 + (lane >> 4) * 8;
      bf16x8 xh = *(const bf16x8*)&Xhs[off];
      bf16x8 xl = *(const bf16x8*)&Xls[off];
      #pragma unroll
      for (int ni = 0; ni < 4; ++ni) {
        acc[mi][ni] = __builtin_amdgcn_mfma_f32_16x16x32_bf16(xh, ahf[ni], acc[mi][ni], 0, 0, 0);
        acc[mi][ni] = __builtin_amdgcn_mfma_f32_16x16x32_bf16(xl, ahf[ni], acc[mi][ni], 0, 0, 0);
        acc[mi][ni] = __builtin_amdgcn_mfma_f32_16x16x32_bf16(xh, alf[ni], acc[mi][ni], 0, 0, 0);
      }
    }
  }
  float* out = P + (long)blockIdx.z * ccols * NN;
  #pragma unroll
  for (int mi = 0; mi < 4; ++mi) {
    int xc = ctile + wc * 64 + mi * 16 + ((lane >> 4) << 2);
    #pragma unroll
    for (int ni = 0; ni < 4; ++ni) {
      int ar = rtile + wr * 64 + ni * 16 + (lane & 15);
      #pragma unroll
      for (int j = 0; j < 4; ++j)
        out[(long)(xc + j) * NN + ar] = acc[mi][ni][j];
    }
  }
}

// ---------------- layers-2/3 GEMM: P = ((1/N)(0.5 J + V) @ X)^T --------------
// A = adj f32 (V = N*adj - 0.5 computed in-flight, single bf16).
// Xg = bf16 [ccols][NN]. cs = colsums of X (DC term). 1-D grid, XCD trio swz.
__launch_bounds__(256, 3)
__global__ void gemm_v(const float* __restrict__ A,
                       const unsigned short* __restrict__ Xg,
                       const float* __restrict__ cs,
                       float* __restrict__ P, int ccols, int klen, int nY) {
  __shared__ unsigned short As[128 * 64];     // 16 KB, 128B rows, XOR-swizzled chunks
  __shared__ unsigned short Xs[2][128 * 64];  // 2 x 16 KB double buffer
  const int tid  = threadIdx.x;
  const int lane = tid & 63;
  const int wave = tid >> 6;
  const int wr = wave & 1;
  const int wc = wave >> 1;

  // XCD swizzle: chunk grid per XCD; y (col-tile) fastest so adj-sharing trios co-locate
  int bid = blockIdx.x;
  int lin = (bid & 7) * ((int)gridDim.x >> 3) + (bid >> 3);
  const int by = lin % nY;
  const int bx = (lin / nY) & 127;
  const int bz = lin / (nY * 128);
  const int rtile = bx * 128;
  const int ctile = by * 128;
  const int kbase = bz * klen;

  // A staging: iter t: row = wave*32 + t*8 + (lane>>3), source chunk ac = lane&7
  const int arow0  = wave * 32 + (lane >> 3);
  const int ac     = lane & 7;
  const int awslot = ac ^ (lane >> 3);     // LDS chunk slot (row&7 == lane>>3)
  const float* aptr = A + (long)(rtile + arow0) * NN + kbase + ac * 8;

  // X staging via global_load_lds: iter t: dest rows (wave*4+t)*8.. linear;
  // per-lane source pre-swizzled: chunk cx = (lane&7)^(lane>>3)
  const int xrow0 = wave * 32 + (lane >> 3);   // (wave*4)*8 + lane>>3
  const int cx    = (lane & 7) ^ (lane >> 3);
  const unsigned short* xptr = Xg + (long)(ctile + xrow0) * NN + kbase + cx * 8;

  f32x4 acc[4][4] = {};
  f32x4 areg[4][2];

  // prologue: A regs step0, X step0 -> Xs[0]
  #pragma unroll
  for (int t = 0; t < 4; ++t) {
    const float* ap = aptr + (long)t * 8 * NN;
    areg[t][0] = *(const f32x4*)ap;
    areg[t][1] = *(const f32x4*)(ap + 4);
    gload_lds16(xptr + (long)t * 8 * NN, &Xs[0][(wave * 4 + t) * 512]);
  }
  aptr += 64; xptr += 64;
  __syncthreads();

  int cur = 0;
  const int nsteps = klen / 64;
  for (int ks = 0; ks < nsteps; ++ks) {
    // convert adj -> V bf16 (v = a*16384 - 0.5)
    u16x8 wv[4];
    #pragma unroll
    for (int t = 0; t < 4; ++t) {
      #pragma unroll
      for (int i = 0; i < 8; ++i) {
        float a = (i < 4) ? areg[t][0][i] : areg[t][1][i - 4];
        float v = fmaf(a, 16384.f, -0.5f);
        wv[t][i] = __builtin_bit_cast(unsigned short, (__bf16)v);
      }
    }
    __syncthreads();                          // B1: prior frag reads complete
    #pragma unroll
    for (int t = 0; t < 4; ++t)
      *(u16x8*)&As[(arow0 + t * 8) * 64 + awslot * 8] = wv[t];
    if (ks + 1 < nsteps) {
      #pragma unroll
      for (int t = 0; t < 4; ++t) {
        gload_lds16(xptr + (long)t * 8 * NN, &Xs[cur ^ 1][(wave * 4 + t) * 512]);
        const float* ap = aptr + (long)t * 8 * NN;
        areg[t][0] = *(const f32x4*)ap;
        areg[t][1] = *(const f32x4*)(ap + 4);
      }
      aptr += 64; xptr += 64;
    }
    __syncthreads();                          // B2: As visible (+vmem drain)
    #pragma unroll
    for (int mk = 0; mk < 2; ++mk) {
      bf16x8 af[4];
      #pragma unroll
      for (int ni = 0; ni < 4; ++ni) {
        int ar = wr * 64 + ni * 16 + (lane & 15);
        int slot = (mk * 4 + (lane >> 4)) ^ (ar & 7);
        af[ni] = *(const bf16x8*)&As[ar * 64 + slot * 8];
      }
      #pragma unroll
      for (int mi = 0; mi < 4; ++mi) {
        int xr = wc * 64 + mi * 16 + (lane & 15);
        int slot = (mk * 4 + (lane >> 4)) ^ (xr & 7);
        bf16x8 xf = *(const bf16x8*)&Xs[cur][xr * 64 + slot * 8];
        #pragma unroll
        for (int ni = 0; ni < 4; ++ni)
          acc[mi][ni] = __builtin_amdgcn_mfma_f32_16x16x32_bf16(xf, af[ni], acc[mi][ni], 0, 0, 0);
      }
    }
    cur ^= 1;
  }

  // epilogue: out = (accV + [z==0] 0.5*colsum_x) / N
  const float scl = 1.f / 16384.f;
  float* out = P + (long)bz * ccols * NN;
  #pragma unroll
  for (int mi = 0; mi < 4; ++mi) {
    int xc = ctile + wc * 64 + mi * 16 + ((lane >> 4) << 2);
    float dc[4];
    #pragma unroll
    for (int j = 0; j < 4; ++j) dc[j] = (bz == 0) ? 0.5f * cs[xc + j] : 0.f;
    #pragma unroll
    for (int ni = 0; ni < 4; ++ni) {
      int ar = rtile + wr * 64 + ni * 16 + (lane & 15);
      #pragma unroll
      for (int j = 0; j < 4; ++j)
        out[(long)(xc + j) * NN + ar] = (acc[mi][ni][j] + dc[j]) * scl;
    }
  }
}

// ---------------- post1a: H1^T = relu((sum_z P) @ w1 + b1) -------------------
__global__ void post1a(const float* __restrict__ P, const float* __restrict__ w1,
                       const float* __restrict__ b1, float* __restrict__ H1T) {
  const int r = blockIdx.x * 256 + threadIdx.x;
  const int e = blockIdx.y;
  for (int c = 0; c < 4; ++c) {        // chunks in-thread: P re-read hits L2
    const int j0 = c * 66;
    float acc[66];
    #pragma unroll
    for (int jj = 0; jj < 66; ++jj) acc[jj] = b1[j0 + jj];
    for (int k = 0; k < 64; ++k) {
      float tv = 0.f;
      #pragma unroll
      for (int z = 0; z < 4; ++z)
        tv += P[(long)(z * 128 + e * 64 + k) * NN + r];
      #pragma unroll
      for (int jj = 0; jj < 66; ++jj)
        acc[jj] = fmaf(tv, w1[k * 264 + j0 + jj], acc[jj]);
    }
    #pragma unroll
    for (int jj = 0; jj < 66; ++jj)
      H1T[(long)(e * 264 + j0 + jj) * NN + r] = fmaxf(acc[jj], 0.f);
  }
}

// ---------------- post1b: G (bf16) [2*192][NN] = (H1 @ w2)^T -----------------
__global__ void post1b(const float* __restrict__ H1T, const float* __restrict__ w2,
                       unsigned short* __restrict__ G) {
  const int r  = blockIdx.x * 256 + threadIdx.x;
  const int e  = blockIdx.y;
  const int q0 = blockIdx.z * 41;
  float acc[41] = {};
  for (int j = 0; j < 264; ++j) {
    float h = H1T[(long)(e * 264 + j) * NN + r];
    #pragma unroll
    for (int qq = 0; qq < 41; ++qq)
      acc[qq] = fmaf(h, w2[j * 164 + q0 + qq], acc[qq]);
  }
  #pragma unroll
  for (int qq = 0; qq < 41; ++qq)
    G[(long)(e * 192 + q0 + qq) * NN + r] =
        __builtin_bit_cast(unsigned short, (__bf16)acc[qq]);
  if (blockIdx.z == 3) {
    for (int q = 164; q < 192; ++q)
      G[(long)(e * 192 + q) * NN + r] = 0;
  }
}

// ---------------- column sums of a bf16 [*][NN] matrix -----------------------
__global__ void colsum_bf16(const unsigned short* __restrict__ X, float* __restrict__ cs) {
  const int c = blockIdx.x;
  const unsigned short* row = X + (long)c * NN;
  float s = 0.f;
  for (int i = threadIdx.x; i < NN; i += 256)
    s += __uint_as_float((unsigned)row[i] << 16);
  __shared__ float red[256];
  red[threadIdx.x] = s;
  __syncthreads();
  for (int off = 128; off > 0; off >>= 1) {
    if (threadIdx.x < off) red[threadIdx.x] += red[threadIdx.x + off];
    __syncthreads();
  }
  if (threadIdx.x == 0) cs[c] = red[0];
}

// ---------------- post2: F (bf16) = (relu(sum_z P + b2) @ w3)^T --------------
__global__ void post2(const float* __restrict__ P, const float* __restrict__ w3,
                      const float* __restrict__ b2, unsigned short* __restrict__ F) {
  const int r = blockIdx.x * 256 + threadIdx.x;
  const int e = blockIdx.y;
  float f[64] = {};
  for (int j = 0; j < 164; ++j) {
    float h = P[(long)(e * 192 + j) * NN + r] + P[(long)(384 + e * 192 + j) * NN + r] + b2[j];
    h = fmaxf(h, 0.f);
    #pragma unroll
    for (int q = 0; q < 64; ++q) f[q] = fmaf(h, w3[j * 64 + q], f[q]);
  }
  #pragma unroll
  for (int q = 0; q < 64; ++q)
    F[(long)(e * 64 + q) * NN + r] = __builtin_bit_cast(unsigned short, (__bf16)f[q]);
}

// ---------------- post3: H3^T = relu(sum_z P + b3) ---------------------------
__global__ void post3(const float* __restrict__ P, const float* __restrict__ b3,
                      float* __restrict__ H3T) {
  const int r = blockIdx.x * 256 + threadIdx.x;
  const int e = blockIdx.y;
  #pragma unroll
  for (int q = 0; q < 64; ++q) {
    float v = b3[q];
    #pragma unroll
    for (int z = 0; z < 4; ++z)
      v += P[(long)(z * 128 + e * 64 + q) * NN + r];
    H3T[(long)(e * 64 + q) * NN + r] = fmaxf(v, 0.f);
  }
}

// ---------------- colsum (f32) of encoder-1 H3 -------------------------------
__global__ void colsum(const float* __restrict__ H3T, float* __restrict__ sums) {
  const int c = blockIdx.x;
  const float* row = H3T + (long)c * NN;
  float s = 0.f;
  for (int i = threadIdx.x; i < NN; i += 256) s += row[i];
  __shared__ float red[256];
  red[threadIdx.x] = s;
  __syncthreads();
  for (int off = 128; off > 0; off >>= 1) {
    if (threadIdx.x < off) red[threadIdx.x] += red[threadIdx.x + off];
    __syncthreads();
  }
  if (threadIdx.x == 0) sums[c] = red[0];
}

// ---------------- c = sigmoid(mean), cw = wd @ c -----------------------------
__global__ void make_cw(const float* __restrict__ sums, const float* __restrict__ wd,
                        float* __restrict__ cw) {
  __shared__ float cv[64];
  const int t = threadIdx.x;
  cv[t] = 1.f / (1.f + expf(-sums[t] / 16384.f));
  __syncthreads();
  float a = 0.f;
  for (int d = 0; d < 64; ++d) a += cv[d] * wd[t * 64 + d];
  cw[t] = a;
}

// ---------------- scores -----------------------------------------------------
__global__ void score(const float* __restrict__ H3T, const float* __restrict__ cw,
                      const float* __restrict__ bdp, const float* __restrict__ sb1,
                      const float* __restrict__ sb2, float* __restrict__ out) {
  const int idx = blockIdx.x * 256 + threadIdx.x;
  const int e = idx >> 14, r = idx & (NN - 1);
  float acc = bdp[0] + (e ? sb2[r] : sb1[r]);
  const float* base = H3T + (long)e * 64 * NN + r;
  #pragma unroll
  for (int j = 0; j < 64; ++j) acc = fmaf(base[(long)j * NN], cw[j], acc);
  out[idx] = acc;
}

extern "C" void kernel_launch(void* const* d_in, const int* in_sizes, int n_in,
                              void* d_out, int out_size, void* d_ws, size_t ws_size,
                              hipStream_t stream) {
  const float* seq1 = (const float*)d_in[0];
  const float* seq2 = (const float*)d_in[1];
  const float* adj  = (const float*)d_in[2];
  const float* sb1  = (const float*)d_in[3];
  const float* sb2  = (const float*)d_in[4];
  const float* w1   = (const float*)d_in[5];
  const float* b1   = (const float*)d_in[6];
  const float* w2   = (const float*)d_in[7];
  const float* b2   = (const float*)d_in[8];
  const float* w3   = (const float*)d_in[9];
  const float* b3   = (const float*)d_in[10];
  const float* wd   = (const float*)d_in[11];
  const float* bd   = (const float*)d_in[12];
  float* out = (float*)d_out;

  // workspace (~118.5 MB), sequential liveness:
  // P region shared by P1 (z4*128), P2 (z2*384), P3 (z4*128) f32 planes.
  char* ws = (char*)d_ws;
  unsigned short* Shi = (unsigned short*)(ws + 0);           //  4,194,304
  unsigned short* Slo = (unsigned short*)(ws + 4194304);     //  4,194,304
  float*          Pp  = (float*)(ws + 8388608);              // 50,331,648 max
  unsigned short* G   = (unsigned short*)(ws + 58720256);    // 12,582,912
  float*          H1T = (float*)(ws + 71303168);             // 34,603,008
  unsigned short* F   = (unsigned short*)(ws + 105906176);   //  4,194,304
  float*          H3T = (float*)(ws + 110100480);            //  8,388,608
  float*          csG = (float*)(ws + 118489088);            //  1,536
  float*          csF = (float*)(ws + 118490624);            //    512
  float*          sums= (float*)(ws + 118491136);            //    256
  float*          cw  = (float*)(ws + 118491392);            //    256

  prep_seq   <<<dim3(256, 2), 256, 0, stream>>>(seq1, seq2, Shi, Slo);
  gemm_adj   <<<dim3(128, 1, 4), 256, 0, stream>>>(adj, Shi, Slo, Pp, 128, 4096);
  post1a     <<<dim3(64, 2), 256, 0, stream>>>(Pp, w1, b1, H1T);
  post1b     <<<dim3(64, 2, 4), 256, 0, stream>>>(H1T, w2, G);
  colsum_bf16<<<384, 256, 0, stream>>>(G, csG);
  gemm_v     <<<768, 256, 0, stream>>>(adj, G, csG, Pp, 384, 8192, 3);
  post2      <<<dim3(64, 2), 256, 0, stream>>>(Pp, w3, b2, F);
  colsum_bf16<<<128, 256, 0, stream>>>(F, csF);
  gemm_v     <<<512, 256, 0, stream>>>(adj, F, csF, Pp, 128, 4096, 1);
  post3      <<<dim3(64, 2), 256, 0, stream>>>(Pp, b3, H3T);
  colsum     <<<64, 256, 0, stream>>>(H3T, sums);
  make_cw    <<<1, 64, 0, stream>>>(sums, wd, cw);
  score      <<<128, 256, 0, stream>>>(H3T, cw, bd, sb1, sb2, out);
}

// Round 4
// 1115.877 us; speedup vs baseline: 1.6085x; 1.1198x over previous
//
#include <hip/hip_runtime.h>
#include <hip/hip_bf16.h>

#define NN 16384

using f32x4  = __attribute__((ext_vector_type(4))) float;
using bf16x8 = __attribute__((ext_vector_type(8))) __bf16;
using u16x8  = __attribute__((ext_vector_type(8))) unsigned short;

__device__ __forceinline__ void gload_lds16(const void* g, void* l) {
  __builtin_amdgcn_global_load_lds(
      (const __attribute__((address_space(1))) unsigned*)g,
      (__attribute__((address_space(3))) unsigned*)l, 16, 0, 0);
}

__device__ __forceinline__ unsigned short bf16r(float x) {
  return __builtin_bit_cast(unsigned short, (__bf16)x);
}

// ---------------- zero the atomic accumulator --------------------------------
__global__ void zero_cs(float* __restrict__ csS) {
  if (threadIdx.x < 128) csS[threadIdx.x] = 0.f;
}

// ---------------- exact f32 colsums of seq1|seq2 -> csS[128] -----------------
__global__ void seqsum(const float* __restrict__ seq1, const float* __restrict__ seq2,
                       float* __restrict__ csS) {
  const int e = blockIdx.x >> 4, chunk = blockIdx.x & 15;
  const float* seq = e ? seq2 : seq1;
  const int g = threadIdx.x >> 4;   // 16 row groups
  const int q = threadIdx.x & 15;   // col quad
  f32x4 acc = {};
  for (int i = 0; i < 64; ++i) {
    int r = chunk * 1024 + i * 16 + g;
    acc += *(const f32x4*)(seq + (long)r * 64 + q * 4);
  }
  __shared__ f32x4 red[256];
  red[threadIdx.x] = acc;
  __syncthreads();
  if (threadIdx.x < 64) {
    int d = threadIdx.x;
    float s = 0.f;
    #pragma unroll
    for (int g2 = 0; g2 < 16; ++g2) {
      f32x4 v = red[g2 * 16 + (d >> 2)];
      s += v[d & 3];
    }
    atomicAdd(&csS[e * 64 + d], s);
  }
}

// ---------------- seq1|seq2 -> S^T bf16 [128][16384] -------------------------
__global__ void prep_seq(const float* __restrict__ seq1, const float* __restrict__ seq2,
                         unsigned short* __restrict__ Shi) {
  const int tid = threadIdx.x;
  const int r0  = blockIdx.x * 64;
  const float* seq = blockIdx.y ? seq2 : seq1;
  __shared__ float t[64][65];
  #pragma unroll
  for (int i = 0; i < 16; ++i) {
    int row = i * 4 + (tid >> 6);
    t[row][tid & 63] = seq[(long)(r0 + row) * 64 + (tid & 63)];
  }
  __syncthreads();
  #pragma unroll
  for (int i = 0; i < 16; ++i) {
    int col = i * 4 + (tid >> 6);
    int rr  = tid & 63;
    Shi[(long)(blockIdx.y * 64 + col) * NN + r0 + rr] = bf16r(t[rr][col]);
  }
}

// ---------------- layer-1 GEMM + V emission ----------------------------------
// P = ((0.5 J + V) @ X)^T / N, V = N*adj - 0.5 (bf16, written to Vg).
// ccols=128, klen=4096, grid 512 (bx 128 x bz 4), nY=1.
__launch_bounds__(256, 3)
__global__ void gemm1(const float* __restrict__ A,
                      const unsigned short* __restrict__ Xg,
                      const float* __restrict__ cs,
                      float* __restrict__ P,
                      unsigned short* __restrict__ Vg) {
  __shared__ unsigned short As[128 * 64];
  __shared__ unsigned short Xs[2][128 * 64];
  const int tid  = threadIdx.x;
  const int lane = tid & 63;
  const int wave = tid >> 6;
  const int wr = wave & 1;
  const int wc = wave >> 1;

  int bid = blockIdx.x;
  int lin = (bid & 7) * ((int)gridDim.x >> 3) + (bid >> 3);
  const int bx = lin & 127;
  const int bz = lin >> 7;                 // 0..3
  const int rtile = bx * 128;
  const int kbase = bz * 4096;

  const int arow0  = wave * 32 + (lane >> 3);
  const int ac     = lane & 7;
  const int awslot = ac ^ (lane >> 3);
  const float* aptr = A + (long)(rtile + arow0) * NN + kbase + ac * 8;
  unsigned short* vptr = Vg + (long)(rtile + arow0) * NN + kbase + ac * 8;

  const int cx = (lane & 7) ^ (lane >> 3);
  const unsigned short* xptr = Xg + (long)arow0 * NN + kbase + cx * 8;

  f32x4 acc[4][4] = {};
  f32x4 areg[4][2];

  #pragma unroll
  for (int t = 0; t < 4; ++t) {
    const float* ap = aptr + (long)t * 8 * NN;
    areg[t][0] = *(const f32x4*)ap;
    areg[t][1] = *(const f32x4*)(ap + 4);
    gload_lds16(xptr + (long)t * 8 * NN, &Xs[0][(wave * 4 + t) * 512]);
  }
  aptr += 64; xptr += 64;
  __syncthreads();

  int cur = 0;
  const int nsteps = 4096 / 64;
  for (int ks = 0; ks < nsteps; ++ks) {
    u16x8 wv[4];
    #pragma unroll
    for (int t = 0; t < 4; ++t) {
      #pragma unroll
      for (int i = 0; i < 8; ++i) {
        float a = (i < 4) ? areg[t][0][i] : areg[t][1][i - 4];
        wv[t][i] = bf16r(fmaf(a, 16384.f, -0.5f));
      }
      *(u16x8*)(vptr + (long)t * 8 * NN) = wv[t];   // emit V for layers 2/3
    }
    vptr += 64;
    __syncthreads();                          // B1
    #pragma unroll
    for (int t = 0; t < 4; ++t)
      *(u16x8*)&As[(arow0 + t * 8) * 64 + awslot * 8] = wv[t];
    if (ks + 1 < nsteps) {
      #pragma unroll
      for (int t = 0; t < 4; ++t) {
        gload_lds16(xptr + (long)t * 8 * NN, &Xs[cur ^ 1][(wave * 4 + t) * 512]);
        const float* ap = aptr + (long)t * 8 * NN;
        areg[t][0] = *(const f32x4*)ap;
        areg[t][1] = *(const f32x4*)(ap + 4);
      }
      aptr += 64; xptr += 64;
    }
    __syncthreads();                          // B2
    #pragma unroll
    for (int mk = 0; mk < 2; ++mk) {
      bf16x8 af[4];
      #pragma unroll
      for (int ni = 0; ni < 4; ++ni) {
        int ar = wr * 64 + ni * 16 + (lane & 15);
        int slot = (mk * 4 + (lane >> 4)) ^ (ar & 7);
        af[ni] = *(const bf16x8*)&As[ar * 64 + slot * 8];
      }
      #pragma unroll
      for (int mi = 0; mi < 4; ++mi) {
        int xr = wc * 64 + mi * 16 + (lane & 15);
        int slot = (mk * 4 + (lane >> 4)) ^ (xr & 7);
        bf16x8 xf = *(const bf16x8*)&Xs[cur][xr * 64 + slot * 8];
        #pragma unroll
        for (int ni = 0; ni < 4; ++ni)
          acc[mi][ni] = __builtin_amdgcn_mfma_f32_16x16x32_bf16(xf, af[ni], acc[mi][ni], 0, 0, 0);
      }
    }
    cur ^= 1;
  }

  const float scl = 1.f / 16384.f;
  float* out = P + (long)bz * 128 * NN;
  #pragma unroll
  for (int mi = 0; mi < 4; ++mi) {
    int xc = wc * 64 + mi * 16 + ((lane >> 4) << 2);
    float dc[4];
    #pragma unroll
    for (int j = 0; j < 4; ++j) dc[j] = (bz == 0) ? 0.5f * cs[xc + j] : 0.f;
    #pragma unroll
    for (int ni = 0; ni < 4; ++ni) {
      int ar = rtile + wr * 64 + ni * 16 + (lane & 15);
      #pragma unroll
      for (int j = 0; j < 4; ++j)
        out[(long)(xc + j) * NN + ar] = (acc[mi][ni][j] + dc[j]) * scl;
    }
  }
}

// ---------------- layers-2/3 GEMM: P = ((0.5 J + V) @ X)^T / N ---------------
// Va = V bf16 [NN][NN]. Xg = bf16 [ccols][NN]. cs = colsums of X.
__launch_bounds__(256, 3)
__global__ void gemm23(const unsigned short* __restrict__ Va,
                       const unsigned short* __restrict__ Xg,
                       const float* __restrict__ cs,
                       float* __restrict__ P, int ccols, int klen, int nY) {
  __shared__ unsigned short As[128 * 64];
  __shared__ unsigned short Xs[2][128 * 64];
  const int tid  = threadIdx.x;
  const int lane = tid & 63;
  const int wave = tid >> 6;
  const int wr = wave & 1;
  const int wc = wave >> 1;

  int bid = blockIdx.x;
  int lin = (bid & 7) * ((int)gridDim.x >> 3) + (bid >> 3);
  const int by = lin % nY;
  const int bx = (lin / nY) & 127;
  const int bz = lin / (nY * 128);
  const int rtile = bx * 128;
  const int ctile = by * 128;
  const int kbase = bz * klen;

  const int arow0  = wave * 32 + (lane >> 3);
  const int ac     = lane & 7;
  const int awslot = ac ^ (lane >> 3);
  const unsigned short* aptr = Va + (long)(rtile + arow0) * NN + kbase + ac * 8;

  const int cx = (lane & 7) ^ (lane >> 3);
  const unsigned short* xptr = Xg + (long)(ctile + arow0) * NN + kbase + cx * 8;

  f32x4 acc[4][4] = {};
  u16x8 av[4];

  #pragma unroll
  for (int t = 0; t < 4; ++t) {
    av[t] = *(const u16x8*)(aptr + (long)t * 8 * NN);
    gload_lds16(xptr + (long)t * 8 * NN, &Xs[0][(wave * 4 + t) * 512]);
  }
  aptr += 64; xptr += 64;
  __syncthreads();

  int cur = 0;
  const int nsteps = klen / 64;
  for (int ks = 0; ks < nsteps; ++ks) {
    __syncthreads();                          // B1
    #pragma unroll
    for (int t = 0; t < 4; ++t)
      *(u16x8*)&As[(arow0 + t * 8) * 64 + awslot * 8] = av[t];
    if (ks + 1 < nsteps) {
      #pragma unroll
      for (int t = 0; t < 4; ++t) {
        gload_lds16(xptr + (long)t * 8 * NN, &Xs[cur ^ 1][(wave * 4 + t) * 512]);
        av[t] = *(const u16x8*)(aptr + (long)t * 8 * NN);
      }
      aptr += 64; xptr += 64;
    }
    __syncthreads();                          // B2
    #pragma unroll
    for (int mk = 0; mk < 2; ++mk) {
      bf16x8 af[4];
      #pragma unroll
      for (int ni = 0; ni < 4; ++ni) {
        int ar = wr * 64 + ni * 16 + (lane & 15);
        int slot = (mk * 4 + (lane >> 4)) ^ (ar & 7);
        af[ni] = *(const bf16x8*)&As[ar * 64 + slot * 8];
      }
      #pragma unroll
      for (int mi = 0; mi < 4; ++mi) {
        int xr = wc * 64 + mi * 16 + (lane & 15);
        int slot = (mk * 4 + (lane >> 4)) ^ (xr & 7);
        bf16x8 xf = *(const bf16x8*)&Xs[cur][xr * 64 + slot * 8];
        #pragma unroll
        for (int ni = 0; ni < 4; ++ni)
          acc[mi][ni] = __builtin_amdgcn_mfma_f32_16x16x32_bf16(xf, af[ni], acc[mi][ni], 0, 0, 0);
      }
    }
    cur ^= 1;
  }

  const float scl = 1.f / 16384.f;
  float* out = P + (long)bz * ccols * NN;
  #pragma unroll
  for (int mi = 0; mi < 4; ++mi) {
    int xc = ctile + wc * 64 + mi * 16 + ((lane >> 4) << 2);
    float dc[4];
    #pragma unroll
    for (int j = 0; j < 4; ++j) dc[j] = (bz == 0) ? 0.5f * cs[xc + j] : 0.f;
    #pragma unroll
    for (int ni = 0; ni < 4; ++ni) {
      int ar = rtile + wr * 64 + ni * 16 + (lane & 15);
      #pragma unroll
      for (int j = 0; j < 4; ++j)
        out[(long)(xc + j) * NN + ar] = (acc[mi][ni][j] + dc[j]) * scl;
    }
  }
}

// ---------------- post1a: H1^T = relu((sum_z P) @ w1 + b1) -------------------
__global__ void post1a(const float* __restrict__ P, const float* __restrict__ w1,
                       const float* __restrict__ b1, float* __restrict__ H1T) {
  const int r = blockIdx.x * 256 + threadIdx.x;
  const int e = blockIdx.y;
  for (int c = blockIdx.z * 2; c < blockIdx.z * 2 + 2; ++c) {
    const int j0 = c * 66;
    float acc[66];
    #pragma unroll
    for (int jj = 0; jj < 66; ++jj) acc[jj] = b1[j0 + jj];
    for (int k = 0; k < 64; ++k) {
      float tv = 0.f;
      #pragma unroll
      for (int z = 0; z < 4; ++z)
        tv += P[(long)(z * 128 + e * 64 + k) * NN + r];
      #pragma unroll
      for (int jj = 0; jj < 66; ++jj)
        acc[jj] = fmaf(tv, w1[k * 264 + j0 + jj], acc[jj]);
    }
    #pragma unroll
    for (int jj = 0; jj < 66; ++jj)
      H1T[(long)(e * 264 + j0 + jj) * NN + r] = fmaxf(acc[jj], 0.f);
  }
}

// ---------------- post1b: G (bf16) [2*192][NN] = (H1 @ w2)^T -----------------
__global__ void post1b(const float* __restrict__ H1T, const float* __restrict__ w2,
                       unsigned short* __restrict__ G) {
  const int r  = blockIdx.x * 256 + threadIdx.x;
  const int e  = blockIdx.y;
  const int q0 = blockIdx.z * 41;
  float acc[41] = {};
  for (int j = 0; j < 264; ++j) {
    float h = H1T[(long)(e * 264 + j) * NN + r];
    #pragma unroll
    for (int qq = 0; qq < 41; ++qq)
      acc[qq] = fmaf(h, w2[j * 164 + q0 + qq], acc[qq]);
  }
  #pragma unroll
  for (int qq = 0; qq < 41; ++qq)
    G[(long)(e * 192 + q0 + qq) * NN + r] = bf16r(acc[qq]);
  if (blockIdx.z == 3) {
    for (int q = 164; q < 192; ++q)
      G[(long)(e * 192 + q) * NN + r] = 0;
  }
}

// ---------------- column sums of a bf16 [*][NN] matrix -----------------------
__global__ void colsum_bf16(const unsigned short* __restrict__ X, float* __restrict__ cs) {
  const int c = blockIdx.x;
  const unsigned short* row = X + (long)c * NN;
  float s = 0.f;
  for (int i = threadIdx.x; i < NN; i += 256)
    s += __uint_as_float((unsigned)row[i] << 16);
  __shared__ float red[256];
  red[threadIdx.x] = s;
  __syncthreads();
  for (int off = 128; off > 0; off >>= 1) {
    if (threadIdx.x < off) red[threadIdx.x] += red[threadIdx.x + off];
    __syncthreads();
  }
  if (threadIdx.x == 0) cs[c] = red[0];
}

// ---------------- post2: F (bf16) = (relu(sum_z P + b2) @ w3)^T --------------
__global__ void post2(const float* __restrict__ P, const float* __restrict__ w3,
                      const float* __restrict__ b2, unsigned short* __restrict__ F) {
  const int r  = blockIdx.x * 256 + threadIdx.x;
  const int e  = blockIdx.y;
  const int q0 = blockIdx.z * 32;
  float f[32] = {};
  for (int j = 0; j < 164; ++j) {
    float h = P[(long)(e * 192 + j) * NN + r] + P[(long)(384 + e * 192 + j) * NN + r] + b2[j];
    h = fmaxf(h, 0.f);
    #pragma unroll
    for (int q = 0; q < 32; ++q) f[q] = fmaf(h, w3[j * 64 + q0 + q], f[q]);
  }
  #pragma unroll
  for (int q = 0; q < 32; ++q)
    F[(long)(e * 64 + q0 + q) * NN + r] = bf16r(f[q]);
}

// ---------------- post3: H3^T = relu(sum_z P + b3) ---------------------------
__global__ void post3(const float* __restrict__ P, const float* __restrict__ b3,
                      float* __restrict__ H3T) {
  const int r = blockIdx.x * 256 + threadIdx.x;
  const int e = blockIdx.y;
  #pragma unroll
  for (int q = 0; q < 64; ++q) {
    float v = b3[q];
    #pragma unroll
    for (int z = 0; z < 4; ++z)
      v += P[(long)(z * 128 + e * 64 + q) * NN + r];
    H3T[(long)(e * 64 + q) * NN + r] = fmaxf(v, 0.f);
  }
}

// ---------------- colsum (f32) of encoder-1 H3 -------------------------------
__global__ void colsum(const float* __restrict__ H3T, float* __restrict__ sums) {
  const int c = blockIdx.x;
  const float* row = H3T + (long)c * NN;
  float s = 0.f;
  for (int i = threadIdx.x; i < NN; i += 256) s += row[i];
  __shared__ float red[256];
  red[threadIdx.x] = s;
  __syncthreads();
  for (int off = 128; off > 0; off >>= 1) {
    if (threadIdx.x < off) red[threadIdx.x] += red[threadIdx.x + off];
    __syncthreads();
  }
  if (threadIdx.x == 0) sums[c] = red[0];
}

// ---------------- c = sigmoid(mean), cw = wd @ c -----------------------------
__global__ void make_cw(const float* __restrict__ sums, const float* __restrict__ wd,
                        float* __restrict__ cw) {
  __shared__ float cv[64];
  const int t = threadIdx.x;
  cv[t] = 1.f / (1.f + expf(-sums[t] / 16384.f));
  __syncthreads();
  float a = 0.f;
  for (int d = 0; d < 64; ++d) a += cv[d] * wd[t * 64 + d];
  cw[t] = a;
}

// ---------------- scores -----------------------------------------------------
__global__ void score(const float* __restrict__ H3T, const float* __restrict__ cw,
                      const float* __restrict__ bdp, const float* __restrict__ sb1,
                      const float* __restrict__ sb2, float* __restrict__ out) {
  const int idx = blockIdx.x * 256 + threadIdx.x;
  const int e = idx >> 14, r = idx & (NN - 1);
  float acc = bdp[0] + (e ? sb2[r] : sb1[r]);
  const float* base = H3T + (long)e * 64 * NN + r;
  #pragma unroll
  for (int j = 0; j < 64; ++j) acc = fmaf(base[(long)j * NN], cw[j], acc);
  out[idx] = acc;
}

extern "C" void kernel_launch(void* const* d_in, const int* in_sizes, int n_in,
                              void* d_out, int out_size, void* d_ws, size_t ws_size,
                              hipStream_t stream) {
  const float* seq1 = (const float*)d_in[0];
  const float* seq2 = (const float*)d_in[1];
  const float* adj  = (const float*)d_in[2];
  const float* sb1  = (const float*)d_in[3];
  const float* sb2  = (const float*)d_in[4];
  const float* w1   = (const float*)d_in[5];
  const float* b1   = (const float*)d_in[6];
  const float* w2   = (const float*)d_in[7];
  const float* b2   = (const float*)d_in[8];
  const float* w3   = (const float*)d_in[9];
  const float* b3   = (const float*)d_in[10];
  const float* wd   = (const float*)d_in[11];
  const float* bd   = (const float*)d_in[12];
  float* out = (float*)d_out;

  // workspace (~651 MB of the 4 GiB d_ws). Liveness is sequential; V persists.
  char* ws = (char*)d_ws;
  unsigned short* Vg  = (unsigned short*)(ws + 0);            // 536,870,912
  unsigned short* Shi = (unsigned short*)(ws + 536870912);    //   4,194,304
  float*          Pp  = (float*)(ws + 541065216);             //  50,331,648 max
  unsigned short* G   = (unsigned short*)(ws + 591396864);    //  12,582,912
  float*          H1T = (float*)(ws + 603979776);             //  34,603,008
  unsigned short* F   = (unsigned short*)(ws + 638582784);    //   4,194,304
  float*          H3T = (float*)(ws + 642777088);             //   8,388,608
  float*          csS = (float*)(ws + 651165696);             //         512
  float*          csG = (float*)(ws + 651166208);             //       1,536
  float*          csF = (float*)(ws + 651167744);             //         512
  float*          sums= (float*)(ws + 651168256);             //         256
  float*          cw  = (float*)(ws + 651168512);             //         256

  zero_cs    <<<1, 128, 0, stream>>>(csS);
  seqsum     <<<32, 256, 0, stream>>>(seq1, seq2, csS);
  prep_seq   <<<dim3(256, 2), 256, 0, stream>>>(seq1, seq2, Shi);
  gemm1      <<<512, 256, 0, stream>>>(adj, Shi, csS, Pp, Vg);
  post1a     <<<dim3(64, 2, 2), 256, 0, stream>>>(Pp, w1, b1, H1T);
  post1b     <<<dim3(64, 2, 4), 256, 0, stream>>>(H1T, w2, G);
  colsum_bf16<<<384, 256, 0, stream>>>(G, csG);
  gemm23     <<<768, 256, 0, stream>>>(Vg, G, csG, Pp, 384, 8192, 3);
  post2      <<<dim3(64, 2, 2), 256, 0, stream>>>(Pp, w3, b2, F);
  colsum_bf16<<<128, 256, 0, stream>>>(F, csF);
  gemm23     <<<512, 256, 0, stream>>>(Vg, F, csF, Pp, 128, 4096, 1);
  post3      <<<dim3(64, 2), 256, 0, stream>>>(Pp, b3, H3T);
  colsum     <<<64, 256, 0, stream>>>(H3T, sums);
  make_cw    <<<1, 64, 0, stream>>>(sums, wd, cw);
  score      <<<128, 256, 0, stream>>>(H3T, cw, bd, sb1, sb2, out);
}